// Round 3
// baseline (282.211 us; speedup 1.0000x reference)
//
#include <hip/hip_runtime.h>

#define HH 1024
#define WW 1024
#define TW 32          // output tile width
#define TH 64          // output tile height
#define SUS 44         // sU stride floats = 11 x 16B units (odd -> conflict-free)
#define SLS 44         // sL stride floats = 11 units (width 40, +4 pad, odd)
#define SGS 36         // sG stride floats = 9 units (odd)
#define DTC (0.1f/3.0f)

// geometry: sU 76r x 44c origin (by-6,bx-6); sL 72r x 40c origin (by-4,bx-4);
// sG 68r x 36c origin (by-2,bx-2) overlays sU; out 64r x 32c.

__global__ __launch_bounds__(256, 4) void pde_layer(
    const float* __restrict__ Uin,
    const float* __restrict__ K1,
    const float* __restrict__ K2,
    const float* __restrict__ Aw,
    float* __restrict__ Uout)
{
    __shared__ __align__(16) float sUG[76 * SUS];          // 13376 B (sG overlays)
    __shared__ __align__(16) float sL0[72 * SLS];          // 12672 B
    __shared__ __align__(16) float sL1[72 * SLS];          // 12672 B
    float* const sU = sUG;
    float* const sG = sUG;

    const int tid = threadIdx.x;
    const int bx = blockIdx.x * TW;
    const int by = blockIdx.y * TH;
    const size_t plane = (size_t)blockIdx.z * (size_t)(HH * WW);
    const float* __restrict__ Ub = Uin + plane;
    float* __restrict__ Ob = Uout + plane;

    // uniform weights -> SGPRs (round-2 evidence: VGPR stayed at 60)
    float w0[25], w1[25], aw[25];
    #pragma unroll
    for (int t = 0; t < 25; ++t) { w0[t] = K1[t]; w1[t] = K1[25 + t]; aw[t] = Aw[t]; }
    const float k2a = K2[0], k2b = K2[1];

    // ---- stage 0: load U tile 76r x 44c (11 units/row) ----
    const bool xedge = (bx == 0) || (bx + TW == WW);
    if (!xedge) {
        // interior: cols bx-6 .. bx+37 never wrap; c = 2 mod 4 -> two 8B loads
        for (int it = tid; it < 76 * 11; it += 256) {
            int r = it / 11;
            int q = it - r * 11;
            int gr = (by + r - 6) & (HH - 1);
            const float* row = Ub + ((size_t)gr << 10);
            int c = bx - 6 + (q << 2);
            float2 a = *(const float2*)(row + c);
            float2 b = *(const float2*)(row + c + 2);
            float4 v; v.x = a.x; v.y = a.y; v.z = b.x; v.w = b.y;
            *(float4*)&sU[r * SUS + (q << 2)] = v;
        }
    } else {
        for (int it = tid; it < 76 * 11; it += 256) {
            int r = it / 11;
            int q = it - r * 11;
            int gr = (by + r - 6) & (HH - 1);
            const float* row = Ub + ((size_t)gr << 10);
            int c = bx - 6 + (q << 2);
            float4 v;
            v.x = row[(c + 0) & (WW - 1)];
            v.y = row[(c + 1) & (WW - 1)];
            v.z = row[(c + 2) & (WW - 1)];
            v.w = row[(c + 3) & (WW - 1)];
            *(float4*)&sU[r * SUS + (q << 2)] = v;
        }
    }
    __syncthreads();

    // ---- stage 1: lam[ch] = relu(conv5(U,K1ch))*K2ch, 72r x 40c, 18x10 items ----
    if (tid < 180) {
        const int rg = tid / 10;
        const int cg = tid - rg * 10;
        const float* src = &sU[(rg * 4) * SUS + cg * 4];
        float acc0[4][4] = {}, acc1[4][4] = {};
        #pragma unroll
        for (int ri = 0; ri < 8; ++ri) {
            float u[8];
            *(float4*)&u[0] = *(const float4*)&src[ri * SUS];
            *(float4*)&u[4] = *(const float4*)&src[ri * SUS + 4];
            #pragma unroll
            for (int k = 0; k < 4; ++k) {
                const int i = ri - k;
                if (i >= 0 && i < 5) {
                    #pragma unroll
                    for (int j = 0; j < 5; ++j) {
                        const float a = w0[i * 5 + j];
                        const float b = w1[i * 5 + j];
                        #pragma unroll
                        for (int cq = 0; cq < 4; ++cq) {
                            acc0[k][cq] = fmaf(u[cq + j], a, acc0[k][cq]);
                            acc1[k][cq] = fmaf(u[cq + j], b, acc1[k][cq]);
                        }
                    }
                }
            }
        }
        #pragma unroll
        for (int k = 0; k < 4; ++k) {
            float4 o0, o1;
            o0.x = fmaxf(acc0[k][0], 0.f) * k2a;  o1.x = fmaxf(acc1[k][0], 0.f) * k2b;
            o0.y = fmaxf(acc0[k][1], 0.f) * k2a;  o1.y = fmaxf(acc1[k][1], 0.f) * k2b;
            o0.z = fmaxf(acc0[k][2], 0.f) * k2a;  o1.z = fmaxf(acc1[k][2], 0.f) * k2b;
            o0.w = fmaxf(acc0[k][3], 0.f) * k2a;  o1.w = fmaxf(acc1[k][3], 0.f) * k2b;
            *(float4*)&sL0[(rg * 4 + k) * SLS + cg * 4] = o0;
            *(float4*)&sL1[(rg * 4 + k) * SLS + cg * 4] = o1;
        }
    }
    __syncthreads();

    // ---- stage 2: grad = sum_ch conv5(lam_ch, flip(K1ch)), 68r x 36c, 17x9 items ----
    if (tid < 153) {
        const int rg = tid / 9;
        const int cg = tid - rg * 9;
        const float* p0 = &sL0[(rg * 4) * SLS + cg * 4];
        const float* p1 = &sL1[(rg * 4) * SLS + cg * 4];
        float acc[4][4] = {};
        #pragma unroll
        for (int ri = 0; ri < 8; ++ri) {
            float u0[8], u1[8];
            *(float4*)&u0[0] = *(const float4*)&p0[ri * SLS];
            *(float4*)&u0[4] = *(const float4*)&p0[ri * SLS + 4];
            *(float4*)&u1[0] = *(const float4*)&p1[ri * SLS];
            *(float4*)&u1[4] = *(const float4*)&p1[ri * SLS + 4];
            #pragma unroll
            for (int k = 0; k < 4; ++k) {
                const int i = ri - k;
                if (i >= 0 && i < 5) {
                    #pragma unroll
                    for (int j = 0; j < 5; ++j) {
                        const float a = w0[24 - (i * 5 + j)];   // flipped (conv_transpose)
                        const float b = w1[24 - (i * 5 + j)];
                        #pragma unroll
                        for (int cq = 0; cq < 4; ++cq) {
                            acc[k][cq] = fmaf(u0[cq + j], a, acc[k][cq]);
                            acc[k][cq] = fmaf(u1[cq + j], b, acc[k][cq]);
                        }
                    }
                }
            }
        }
        #pragma unroll
        for (int k = 0; k < 4; ++k) {
            float4 o; o.x = acc[k][0]; o.y = acc[k][1]; o.z = acc[k][2]; o.w = acc[k][3];
            *(float4*)&sG[(rg * 4 + k) * SGS + cg * 4] = o;   // overlays sU (done with it)
        }
    }
    __syncthreads();

    // ---- stage 3: out = U + dt/3 * conv5(grad, A), 64r x 32c, 16x8 items ----
    if (tid < 128) {
        const int rg = tid >> 3;
        const int cg = tid & 7;
        const float* p = &sG[(rg * 4) * SGS + cg * 4];
        float acc[4][4] = {};
        #pragma unroll
        for (int ri = 0; ri < 8; ++ri) {
            float u[8];
            *(float4*)&u[0] = *(const float4*)&p[ri * SGS];
            *(float4*)&u[4] = *(const float4*)&p[ri * SGS + 4];
            #pragma unroll
            for (int k = 0; k < 4; ++k) {
                const int i = ri - k;
                if (i >= 0 && i < 5) {
                    #pragma unroll
                    for (int j = 0; j < 5; ++j) {
                        const float a = aw[i * 5 + j];
                        #pragma unroll
                        for (int cq = 0; cq < 4; ++cq)
                            acc[k][cq] = fmaf(u[cq + j], a, acc[k][cq]);
                    }
                }
            }
        }
        #pragma unroll
        for (int k = 0; k < 4; ++k) {
            const int gy = by + rg * 4 + k;
            const int gx = bx + cg * 4;
            float4 id = *(const float4*)&Ub[((size_t)gy << 10) + gx];  // identity (aligned)
            float4 o;
            o.x = id.x + DTC * acc[k][0];
            o.y = id.y + DTC * acc[k][1];
            o.z = id.z + DTC * acc[k][2];
            o.w = id.w + DTC * acc[k][3];
            *(float4*)&Ob[((size_t)gy << 10) + gx] = o;
        }
    }
}

extern "C" void kernel_launch(void* const* d_in, const int* in_sizes, int n_in,
                              void* d_out, int out_size, void* d_ws, size_t ws_size,
                              hipStream_t stream) {
    const float* U  = (const float*)d_in[0];
    const float* K1 = (const float*)d_in[1];
    const float* K2 = (const float*)d_in[2];
    const float* Aw = (const float*)d_in[3];
    float* out = (float*)d_out;
    float* ws  = (float*)d_ws;

    const int B = in_sizes[0] / (HH * WW);   // 16
    dim3 grid(WW / TW, HH / TH, B);

    // 3 Euler layers; ping-pong in -> out -> ws -> out
    pde_layer<<<grid, 256, 0, stream>>>(U,   K1, K2, Aw, out);
    pde_layer<<<grid, 256, 0, stream>>>(out, K1, K2, Aw, ws);
    pde_layer<<<grid, 256, 0, stream>>>(ws,  K1, K2, Aw, out);
}

// Round 4
// 269.248 us; speedup vs baseline: 1.0481x; 1.0481x over previous
//
#include <hip/hip_runtime.h>

#define HH 1024
#define WW 1024
#define TW 64          // output tile width
#define TH 32          // output tile height
#define SUS 76         // sU stride floats (44 rows,  cols bx-6..bx+69)
#define SLS 76         // sL stride floats (40 rows,  cols bx-4..bx+67, 72 used)
#define SGS 68         // sG stride floats (36 rows,  cols bx-2..bx+65) overlays sL
#define DTC (0.1f/3.0f)

__global__ __launch_bounds__(256, 6) void pde_layer(
    const float* __restrict__ Uin,
    const float* __restrict__ K1,
    const float* __restrict__ K2,
    const float* __restrict__ Aw,
    float* __restrict__ Uout)
{
    __shared__ __align__(16) float sU[44 * SUS];    // 13376 B (stays intact for identity)
    __shared__ __align__(16) float sLG[40 * SLS];   // 12160 B: lam0, lam1, then grad
    float* const sL = sLG;
    float* const sG = sLG;

    const int tid = threadIdx.x;
    const int bx = blockIdx.x * TW;
    const int by = blockIdx.y * TH;
    const size_t plane = (size_t)blockIdx.z * (size_t)(HH * WW);
    const float* __restrict__ Ub = Uin + plane;
    float* __restrict__ Ob = Uout + plane;

    // uniform weights -> SGPRs
    float w0[25], w1[25], aw[25];
    #pragma unroll
    for (int t = 0; t < 25; ++t) { w0[t] = K1[t]; w1[t] = K1[25 + t]; aw[t] = Aw[t]; }
    const float k2a = K2[0], k2b = K2[1];

    // ---- stage 0: load U tile 44r x 76c ----
    const bool xedge = (bx == 0) || (bx + TW == WW);
    if (!xedge) {
        for (int it = tid; it < 44 * 19; it += 256) {
            int r = it / 19, q = it - r * 19;
            int gr = (by + r - 6) & (HH - 1);
            const float* row = Ub + ((size_t)gr << 10);
            int c = bx - 6 + (q << 2);
            float2 a = *(const float2*)(row + c);
            float2 b = *(const float2*)(row + c + 2);
            float4 v; v.x = a.x; v.y = a.y; v.z = b.x; v.w = b.y;
            *(float4*)&sU[r * SUS + (q << 2)] = v;
        }
    } else {
        for (int it = tid; it < 44 * 19; it += 256) {
            int r = it / 19, q = it - r * 19;
            int gr = (by + r - 6) & (HH - 1);
            const float* row = Ub + ((size_t)gr << 10);
            int c = bx - 6 + (q << 2);
            float4 v;
            v.x = row[(c + 0) & (WW - 1)];
            v.y = row[(c + 1) & (WW - 1)];
            v.z = row[(c + 2) & (WW - 1)];
            v.w = row[(c + 3) & (WW - 1)];
            *(float4*)&sU[r * SUS + (q << 2)] = v;
        }
    }
    __syncthreads();

    // persistent per-thread state
    float acc1[4][4];   // lam channel-1, parked across stage 2a
    float gacc[4][4];   // grad accumulator, parked across stage 1b

    const int rg1 = tid / 18, cg1 = tid - (tid / 18) * 18;  // 10 x 18 = 180 items, 40r x 72c
    const int rg2 = tid / 17, cg2 = tid - (tid / 17) * 17;  // 9 x 17 = 153 items, 36r x 68c
    const bool s1 = (tid < 180);
    const bool s2 = (tid < 153);

    // ---- stage 1a: both lam channels from one sU pass; write lam0, park lam1 ----
    if (s1) {
        const float* src = &sU[(rg1 * 4) * SUS + cg1 * 4];
        float acc0[4][4] = {};
        #pragma unroll
        for (int k = 0; k < 4; ++k)
            #pragma unroll
            for (int c = 0; c < 4; ++c) acc1[k][c] = 0.f;
        #pragma unroll
        for (int ri = 0; ri < 8; ++ri) {
            float u[8];
            *(float4*)&u[0] = *(const float4*)&src[ri * SUS];
            *(float4*)&u[4] = *(const float4*)&src[ri * SUS + 4];
            #pragma unroll
            for (int k = 0; k < 4; ++k) {
                const int i = ri - k;
                if (i >= 0 && i < 5) {
                    #pragma unroll
                    for (int j = 0; j < 5; ++j) {
                        const float a = w0[i * 5 + j];
                        const float b = w1[i * 5 + j];
                        #pragma unroll
                        for (int cq = 0; cq < 4; ++cq) {
                            acc0[k][cq] = fmaf(u[cq + j], a, acc0[k][cq]);
                            acc1[k][cq] = fmaf(u[cq + j], b, acc1[k][cq]);
                        }
                    }
                }
            }
        }
        #pragma unroll
        for (int k = 0; k < 4; ++k) {
            float4 o;
            o.x = fmaxf(acc0[k][0], 0.f) * k2a;
            o.y = fmaxf(acc0[k][1], 0.f) * k2a;
            o.z = fmaxf(acc0[k][2], 0.f) * k2a;
            o.w = fmaxf(acc0[k][3], 0.f) * k2a;
            *(float4*)&sL[(rg1 * 4 + k) * SLS + cg1 * 4] = o;
        }
    }
    __syncthreads();

    // ---- stage 2a: grad += conv5(lam0, flip(w0)) ----
    if (s2) {
        #pragma unroll
        for (int k = 0; k < 4; ++k)
            #pragma unroll
            for (int c = 0; c < 4; ++c) gacc[k][c] = 0.f;
        const float* p = &sL[(rg2 * 4) * SLS + cg2 * 4];
        #pragma unroll
        for (int ri = 0; ri < 8; ++ri) {
            float u[8];
            *(float4*)&u[0] = *(const float4*)&p[ri * SLS];
            *(float4*)&u[4] = *(const float4*)&p[ri * SLS + 4];
            #pragma unroll
            for (int k = 0; k < 4; ++k) {
                const int i = ri - k;
                if (i >= 0 && i < 5) {
                    #pragma unroll
                    for (int j = 0; j < 5; ++j) {
                        const float a = w0[24 - (i * 5 + j)];   // flipped
                        #pragma unroll
                        for (int cq = 0; cq < 4; ++cq)
                            gacc[k][cq] = fmaf(u[cq + j], a, gacc[k][cq]);
                    }
                }
            }
        }
    }
    __syncthreads();

    // ---- stage 1b: write parked lam1 into sL ----
    if (s1) {
        #pragma unroll
        for (int k = 0; k < 4; ++k) {
            float4 o;
            o.x = fmaxf(acc1[k][0], 0.f) * k2b;
            o.y = fmaxf(acc1[k][1], 0.f) * k2b;
            o.z = fmaxf(acc1[k][2], 0.f) * k2b;
            o.w = fmaxf(acc1[k][3], 0.f) * k2b;
            *(float4*)&sL[(rg1 * 4 + k) * SLS + cg1 * 4] = o;
        }
    }
    __syncthreads();

    // ---- stage 2b: grad += conv5(lam1, flip(w1)) ----
    if (s2) {
        const float* p = &sL[(rg2 * 4) * SLS + cg2 * 4];
        #pragma unroll
        for (int ri = 0; ri < 8; ++ri) {
            float u[8];
            *(float4*)&u[0] = *(const float4*)&p[ri * SLS];
            *(float4*)&u[4] = *(const float4*)&p[ri * SLS + 4];
            #pragma unroll
            for (int k = 0; k < 4; ++k) {
                const int i = ri - k;
                if (i >= 0 && i < 5) {
                    #pragma unroll
                    for (int j = 0; j < 5; ++j) {
                        const float a = w1[24 - (i * 5 + j)];   // flipped
                        #pragma unroll
                        for (int cq = 0; cq < 4; ++cq)
                            gacc[k][cq] = fmaf(u[cq + j], a, gacc[k][cq]);
                    }
                }
            }
        }
    }
    __syncthreads();

    // ---- write grad -> sG (overlays sL; all sL reads complete) ----
    if (s2) {
        #pragma unroll
        for (int k = 0; k < 4; ++k) {
            float4 o; o.x = gacc[k][0]; o.y = gacc[k][1]; o.z = gacc[k][2]; o.w = gacc[k][3];
            *(float4*)&sG[(rg2 * 4 + k) * SGS + cg2 * 4] = o;
        }
    }
    __syncthreads();

    // ---- stage 3: out = U + dt/3 * conv5(grad, A); identity from sU ----
    if (tid < 128) {
        const int rg = tid >> 4;
        const int cg = tid & 15;
        const float* p = &sG[(rg * 4) * SGS + cg * 4];
        float acc[4][4] = {};
        #pragma unroll
        for (int ri = 0; ri < 8; ++ri) {
            float u[8];
            *(float4*)&u[0] = *(const float4*)&p[ri * SGS];
            *(float4*)&u[4] = *(const float4*)&p[ri * SGS + 4];
            #pragma unroll
            for (int k = 0; k < 4; ++k) {
                const int i = ri - k;
                if (i >= 0 && i < 5) {
                    #pragma unroll
                    for (int j = 0; j < 5; ++j) {
                        const float a = aw[i * 5 + j];
                        #pragma unroll
                        for (int cq = 0; cq < 4; ++cq)
                            acc[k][cq] = fmaf(u[cq + j], a, acc[k][cq]);
                    }
                }
            }
        }
        #pragma unroll
        for (int k = 0; k < 4; ++k) {
            const int r = rg * 4 + k;
            // identity from sU (8B-aligned: col offset 6 + cg*4)
            float2 i0 = *(const float2*)&sU[(r + 6) * SUS + cg * 4 + 6];
            float2 i1 = *(const float2*)&sU[(r + 6) * SUS + cg * 4 + 8];
            float4 o;
            o.x = i0.x + DTC * acc[k][0];
            o.y = i0.y + DTC * acc[k][1];
            o.z = i1.x + DTC * acc[k][2];
            o.w = i1.y + DTC * acc[k][3];
            *(float4*)&Ob[((size_t)(by + r) << 10) + bx + cg * 4] = o;
        }
    }
}

extern "C" void kernel_launch(void* const* d_in, const int* in_sizes, int n_in,
                              void* d_out, int out_size, void* d_ws, size_t ws_size,
                              hipStream_t stream) {
    const float* U  = (const float*)d_in[0];
    const float* K1 = (const float*)d_in[1];
    const float* K2 = (const float*)d_in[2];
    const float* Aw = (const float*)d_in[3];
    float* out = (float*)d_out;
    float* ws  = (float*)d_ws;

    const int B = in_sizes[0] / (HH * WW);   // 16
    dim3 grid(WW / TW, HH / TH, B);

    // 3 Euler layers; ping-pong in -> out -> ws -> out
    pde_layer<<<grid, 256, 0, stream>>>(U,   K1, K2, Aw, out);
    pde_layer<<<grid, 256, 0, stream>>>(out, K1, K2, Aw, ws);
    pde_layer<<<grid, 256, 0, stream>>>(ws,  K1, K2, Aw, out);
}